// Round 1
// baseline (193.303 us; speedup 1.0000x reference)
//
#include <hip/hip_runtime.h>
#include <math.h>

#define BATCH   4096
#define N_NODES 20000
#define H       4
#define BLOCK   1024
#define NW      (BLOCK / 64)

__device__ __forceinline__ float waveSum(float v) {
#pragma unroll
    for (int off = 32; off > 0; off >>= 1) v += __shfl_xor(v, off);
    return v;
}
__device__ __forceinline__ float waveMax(float v) {
#pragma unroll
    for (int off = 32; off > 0; off >>= 1) v = fmaxf(v, __shfl_xor(v, off));
    return v;
}

__global__ __launch_bounds__(BLOCK) void tax_main(
    const float* __restrict__ y_pred,
    const float* __restrict__ y_true,
    const int*   __restrict__ parents,
    const float* __restrict__ alpha,
    float*       __restrict__ partial)
{
    constexpr int LSTART[H] = {0, 100, 1100, 6100};
    constexpr int LSIZE[H]  = {100, 1000, 5000, 13900};

    __shared__ __align__(16) float row[N_NODES];
    __shared__ float red[NW];
    __shared__ float red4[4][NW];
    __shared__ float invZ_s[H];

    const int tid = threadIdx.x;
    const int b   = blockIdx.x;
    const int wid = tid >> 6;
    const int lid = tid & 63;

    // ---- stage the full row into LDS (coalesced float4) ----
    const float4* src4 = reinterpret_cast<const float4*>(y_pred + (size_t)b * N_NODES);
    float4* row4 = reinterpret_cast<float4*>(row);
    for (int i = tid; i < N_NODES / 4; i += BLOCK) row4[i] = src4[i];
    __syncthreads();

    // ---- per-layer max & Z; overwrite row with e = exp(y - m) ----
    for (int l = 0; l < H; ++l) {
        const int s = LSTART[l], n = LSIZE[l];

        float m = -INFINITY;
        for (int i = s / 4 + tid; i < (s + n) / 4; i += BLOCK) {
            float4 v = row4[i];
            m = fmaxf(m, fmaxf(fmaxf(v.x, v.y), fmaxf(v.z, v.w)));
        }
        m = waveMax(m);
        if (lid == 0) red[wid] = m;
        __syncthreads();
        if (wid == 0) {
            float x = (lid < NW) ? red[lid] : -INFINITY;
            x = waveMax(x);
            if (lid == 0) red[0] = x;
        }
        __syncthreads();
        m = red[0];
        __syncthreads();   // protect red[] before reuse

        float z = 0.f;
        for (int i = s / 4 + tid; i < (s + n) / 4; i += BLOCK) {
            float4 v = row4[i];
            v.x = __expf(v.x - m); v.y = __expf(v.y - m);
            v.z = __expf(v.z - m); v.w = __expf(v.w - m);
            row4[i] = v;
            z += v.x + v.y + v.z + v.w;
        }
        z = waveSum(z);
        if (lid == 0) red[wid] = z;
        __syncthreads();
        if (wid == 0) {
            float x = (lid < NW) ? red[lid] : 0.f;
            x = waveSum(x);
            if (lid == 0) invZ_s[l] = 1.f / x;
        }
        __syncthreads();
    }

    // ---- per-layer loss terms (stream y_true once; parent gathers from LDS) ----
    float result = 0.f;   // meaningful only where reduced below
    for (int l = 1; l < H; ++l) {
        const int s = LSTART[l], n = LSIZE[l];
        const float invZ  = invZ_s[l];
        const float invZp = invZ_s[l - 1];
        const float4* yt4 = reinterpret_cast<const float4*>(y_true + (size_t)b * N_NODES + s);
        const int4*   pa4 = reinterpret_cast<const int4*>(parents + s);

        float S = 0.f, dot = 0.f, D = 0.f, yts = 0.f;
        for (int i = tid; i < n / 4; i += BLOCK) {
            float4 e  = row4[s / 4 + i];
            float4 yt = yt4[i];
            int4   pa = pa4[i];
            float p0 = e.x * invZ, p1 = e.y * invZ, p2 = e.z * invZ, p3 = e.w * invZ;
            S   += __expf(p0) + __expf(p1) + __expf(p2) + __expf(p3);
            dot += yt.x * p0 + yt.y * p1 + yt.z * p2 + yt.w * p3;
            yts += yt.x + yt.y + yt.z + yt.w;
            D += fmaxf(p0 - row[pa.x] * invZp, 0.f)
               + fmaxf(p1 - row[pa.y] * invZp, 0.f)
               + fmaxf(p2 - row[pa.z] * invZp, 0.f)
               + fmaxf(p3 - row[pa.w] * invZp, 0.f);
        }

        S = waveSum(S); dot = waveSum(dot); D = waveSum(D); yts = waveSum(yts);
        if (lid == 0) { red4[0][wid] = S; red4[1][wid] = dot; red4[2][wid] = D; red4[3][wid] = yts; }
        __syncthreads();
        if (wid == 0) {
            float a0 = (lid < NW) ? red4[0][lid] : 0.f;
            float a1 = (lid < NW) ? red4[1][lid] : 0.f;
            float a2 = (lid < NW) ? red4[2][lid] : 0.f;
            float a3 = (lid < NW) ? red4[3][lid] : 0.f;
            a0 = waveSum(a0); a1 = waveSum(a1); a2 = waveSum(a2); a3 = waveSum(a3);
            if (lid == 0) {
                float cce = logf(a0) * a3 - a1;   // logsumexp(p)*sum(y_true) - dot(y_true, p)
                float d   = a2 / (float)n;
                result += alpha[l] * (cce + d);
            }
        }
        __syncthreads();   // protect red4[] before reuse
    }

    if (tid == 0) partial[b] = result;
}

__global__ __launch_bounds__(1024) void tax_reduce(
    const float* __restrict__ partial, float* __restrict__ out)
{
    __shared__ float red[16];
    const int tid = threadIdx.x, wid = tid >> 6, lid = tid & 63;
    float v = 0.f;
    for (int i = tid; i < BATCH; i += 1024) v += partial[i];
    v = waveSum(v);
    if (lid == 0) red[wid] = v;
    __syncthreads();
    if (wid == 0) {
        float x = (lid < 16) ? red[lid] : 0.f;
        x = waveSum(x);
        if (lid == 0) out[0] = x * (1.0f / (float)BATCH);
    }
}

extern "C" void kernel_launch(void* const* d_in, const int* in_sizes, int n_in,
                              void* d_out, int out_size, void* d_ws, size_t ws_size,
                              hipStream_t stream) {
    const float* y_pred  = (const float*)d_in[0];
    const float* y_true  = (const float*)d_in[1];
    const int*   parents = (const int*)d_in[2];
    const float* alpha   = (const float*)d_in[3];
    float* partial = (float*)d_ws;           // BATCH floats = 16 KB scratch
    float* out     = (float*)d_out;

    tax_main<<<dim3(BATCH), dim3(BLOCK), 0, stream>>>(y_pred, y_true, parents, alpha, partial);
    tax_reduce<<<dim3(1), dim3(1024), 0, stream>>>(partial, out);
}

// Round 2
// 129.233 us; speedup vs baseline: 1.4958x; 1.4958x over previous
//
#include <hip/hip_runtime.h>
#include <math.h>

#define BATCH   4096
#define N_NODES 20000
#define H       4
#define BLOCK   512
#define NW      (BLOCK / 64)

__device__ __forceinline__ float waveSum(float v) {
#pragma unroll
    for (int off = 32; off > 0; off >>= 1) v += __shfl_xor(v, off);
    return v;
}

// bf16 helpers (round-to-nearest), raw bit ops
__device__ __forceinline__ ushort f2bf(float x) {
    unsigned u = __float_as_uint(x);
    u = (u + 0x7FFFu + ((u >> 16) & 1u)) >> 16;
    return (ushort)u;
}
__device__ __forceinline__ float bf2f(ushort h) {
    return __uint_as_float(((unsigned)h) << 16);
}

// online-softmax merge of (m,z) pairs; m init = -1e30f (finite, so no NaN path)
__device__ __forceinline__ void mzMerge(float& m, float& z, float m2, float z2) {
    float mn = fmaxf(m, m2);
    z = z * __expf(m - mn) + z2 * __expf(m2 - mn);
    m = mn;
}

__global__ __launch_bounds__(BLOCK, 8) void tax_main(
    const float* __restrict__ y_pred,
    const float* __restrict__ y_true,
    const int*   __restrict__ parents,
    const float* __restrict__ alpha,
    float*       __restrict__ partial)
{
    constexpr int LSTART[H] = {0, 100, 1100, 6100};
    constexpr int LSIZE[H]  = {100, 1000, 5000, 13900};

    __shared__ __align__(8) ushort row_bf[N_NODES];   // 40,000 B
    __shared__ float sc[112];
    __shared__ float m_s[H], invZ_s[H];

    const int tid = threadIdx.x;
    const int b   = blockIdx.x;
    const int wid = tid >> 6;
    const int lid = tid & 63;

    const float4* src4 = reinterpret_cast<const float4*>(y_pred + (size_t)b * N_NODES);

    // ---- phase 1: stream y_pred once: stage bf16 to LDS + online (m,z) per layer ----
    float mL[H], zL[H];
#pragma unroll
    for (int l = 0; l < H; ++l) { mL[l] = -1e30f; zL[l] = 0.f; }

#pragma unroll
    for (int l = 0; l < H; ++l) {
        const int sq = LSTART[l] / 4, nq = LSIZE[l] / 4;
        for (int i = tid; i < nq; i += BLOCK) {
            float4 v = src4[sq + i];
            ushort4 h;
            h.x = f2bf(v.x); h.y = f2bf(v.y); h.z = f2bf(v.z); h.w = f2bf(v.w);
            *reinterpret_cast<ushort4*>(&row_bf[4 * (sq + i)]) = h;
            float qm = fmaxf(fmaxf(v.x, v.y), fmaxf(v.z, v.w));
            float mn = fmaxf(mL[l], qm);
            zL[l] = zL[l] * __expf(mL[l] - mn)
                  + __expf(v.x - mn) + __expf(v.y - mn)
                  + __expf(v.z - mn) + __expf(v.w - mn);
            mL[l] = mn;
        }
    }

    // wave-level (m,z) reduce for all 4 layers (register-only)
#pragma unroll
    for (int l = 0; l < H; ++l) {
#pragma unroll
        for (int off = 32; off > 0; off >>= 1) {
            float m2 = __shfl_xor(mL[l], off);
            float z2 = __shfl_xor(zL[l], off);
            mzMerge(mL[l], zL[l], m2, z2);
        }
    }
    if (lid == 0) {
#pragma unroll
        for (int l = 0; l < H; ++l) {
            sc[wid * 8 + l * 2]     = mL[l];
            sc[wid * 8 + l * 2 + 1] = zL[l];
        }
    }
    __syncthreads();   // also covers row_bf staging
    if (tid < H) {
        float m = -1e30f, z = 0.f;
        for (int w = 0; w < NW; ++w)
            mzMerge(m, z, sc[w * 8 + tid * 2], sc[w * 8 + tid * 2 + 1]);
        m_s[tid]    = m;
        invZ_s[tid] = 1.f / z;
    }
    __syncthreads();

    // ---- phase 2: stream y_true once; p and parent-p recomputed from LDS bf16 ----
#pragma unroll
    for (int l = 1; l < H; ++l) {
        const int s = LSTART[l], nq = LSIZE[l] / 4;
        const float invZ  = invZ_s[l],     m  = m_s[l];
        const float invZp = invZ_s[l - 1], mp = m_s[l - 1];
        const float4* yt4 = reinterpret_cast<const float4*>(y_true + (size_t)b * N_NODES + s);
        const int4*   pa4 = reinterpret_cast<const int4*>(parents + s);

        float S = 0.f, dot = 0.f, D = 0.f, yts = 0.f;
        for (int i = tid; i < nq; i += BLOCK) {
            ushort4 yh = *reinterpret_cast<const ushort4*>(&row_bf[s + 4 * i]);
            float4  yt = yt4[i];
            int4    pa = pa4[i];
            float p0 = __expf(bf2f(yh.x) - m) * invZ;
            float p1 = __expf(bf2f(yh.y) - m) * invZ;
            float p2 = __expf(bf2f(yh.z) - m) * invZ;
            float p3 = __expf(bf2f(yh.w) - m) * invZ;
            float pp0 = __expf(bf2f(row_bf[pa.x]) - mp) * invZp;
            float pp1 = __expf(bf2f(row_bf[pa.y]) - mp) * invZp;
            float pp2 = __expf(bf2f(row_bf[pa.z]) - mp) * invZp;
            float pp3 = __expf(bf2f(row_bf[pa.w]) - mp) * invZp;
            S   += __expf(p0) + __expf(p1) + __expf(p2) + __expf(p3);
            dot += yt.x * p0 + yt.y * p1 + yt.z * p2 + yt.w * p3;
            yts += yt.x + yt.y + yt.z + yt.w;
            D += fmaxf(p0 - pp0, 0.f) + fmaxf(p1 - pp1, 0.f)
               + fmaxf(p2 - pp2, 0.f) + fmaxf(p3 - pp3, 0.f);
        }

        S = waveSum(S); dot = waveSum(dot); D = waveSum(D); yts = waveSum(yts);
        if (lid == 0) {
            sc[wid * 12 + (l - 1) * 4 + 0] = S;
            sc[wid * 12 + (l - 1) * 4 + 1] = dot;
            sc[wid * 12 + (l - 1) * 4 + 2] = D;
            sc[wid * 12 + (l - 1) * 4 + 3] = yts;
        }
    }
    __syncthreads();

    if (tid < 12) {
        float a = 0.f;
        for (int w = 0; w < NW; ++w) a += sc[w * 12 + tid];
        sc[96 + tid] = a;
    }
    __syncthreads();

    if (tid == 0) {
        float loss = 0.f;
#pragma unroll
        for (int l = 1; l < H; ++l) {
            float S   = sc[96 + (l - 1) * 4 + 0];
            float dot = sc[96 + (l - 1) * 4 + 1];
            float D   = sc[96 + (l - 1) * 4 + 2];
            float yts = sc[96 + (l - 1) * 4 + 3];
            loss += alpha[l] * (logf(S) * yts - dot + D / (float)LSIZE[l]);
        }
        partial[b] = loss;
    }
}

__global__ __launch_bounds__(1024) void tax_reduce(
    const float* __restrict__ partial, float* __restrict__ out)
{
    __shared__ float red[16];
    const int tid = threadIdx.x, wid = tid >> 6, lid = tid & 63;
    float v = 0.f;
    for (int i = tid; i < BATCH; i += 1024) v += partial[i];
    v = waveSum(v);
    if (lid == 0) red[wid] = v;
    __syncthreads();
    if (wid == 0) {
        float x = (lid < 16) ? red[lid] : 0.f;
        x = waveSum(x);
        if (lid == 0) out[0] = x * (1.0f / (float)BATCH);
    }
}

extern "C" void kernel_launch(void* const* d_in, const int* in_sizes, int n_in,
                              void* d_out, int out_size, void* d_ws, size_t ws_size,
                              hipStream_t stream) {
    const float* y_pred  = (const float*)d_in[0];
    const float* y_true  = (const float*)d_in[1];
    const int*   parents = (const int*)d_in[2];
    const float* alpha   = (const float*)d_in[3];
    float* partial = (float*)d_ws;           // BATCH floats = 16 KB scratch
    float* out     = (float*)d_out;

    tax_main<<<dim3(BATCH), dim3(BLOCK), 0, stream>>>(y_pred, y_true, parents, alpha, partial);
    tax_reduce<<<dim3(1), dim3(1024), 0, stream>>>(partial, out);
}